// Round 9
// baseline (794.570 us; speedup 1.0000x reference)
//
#include <hip/hip_runtime.h>
#include <cstddef>
#include <cstdint>
#include <math.h>

#define BATCH   2
#define LSEQ    4096
#define DMODEL  2048
#define DSTATE  128
#define HDIM    64
#define CHUNK   256
#define DINNER  4096
#define NHEADS  64
#define CONVD   4352
#define DPROJ   8512
#define NCHUNK  16
#define MROWS   (BATCH*LSEQ)
#define NPAD2   8704   // 34*256, padded N for in_proj (256-tile)

typedef unsigned short bf16_t;
union U4 { uint4 u; unsigned short s[8]; };

typedef __attribute__((ext_vector_type(8))) short short8;
typedef __attribute__((ext_vector_type(4))) float f32x4;
union S8 { short8 v; unsigned short s[8]; };

__device__ __forceinline__ float b2f(unsigned short u) {
    union { unsigned int i; float f; } v; v.i = ((unsigned int)u) << 16; return v.f;
}
__device__ __forceinline__ unsigned short f2b(float f) {
    union { float f; unsigned int i; } v; v.f = f;
    unsigned int r = v.i + 0x7fffu + ((v.i >> 16) & 1u);   // round-to-nearest-even
    return (unsigned short)(r >> 16);
}

// async global->LDS, 16B per lane; LDS dest = wave-uniform base + lane*16 (HW)
__device__ __forceinline__ void gload_lds16(const void* g, void* l) {
    auto gp = reinterpret_cast<const __attribute__((address_space(1))) unsigned int*>(
        reinterpret_cast<uintptr_t>(g));
    auto lp = reinterpret_cast<__attribute__((address_space(3))) unsigned int*>(
        reinterpret_cast<uintptr_t>(l));
    __builtin_amdgcn_global_load_lds(gp, lp, 16, 0, 0);
}

// ---------------------------------------------------------------------------
// cast u (fp32) -> bf16, contiguous
// ---------------------------------------------------------------------------
__global__ __launch_bounds__(256) void cast_bf16(const float* __restrict__ in,
                                                 bf16_t* __restrict__ out, size_t n8) {
    size_t i = (size_t)blockIdx.x * 256 + threadIdx.x;
    if (i >= n8) return;
    const float4 a = *(const float4*)(in + i * 8);
    const float4 b = *(const float4*)(in + i * 8 + 4);
    U4 o;
    o.s[0]=f2b(a.x); o.s[1]=f2b(a.y); o.s[2]=f2b(a.z); o.s[3]=f2b(a.w);
    o.s[4]=f2b(b.x); o.s[5]=f2b(b.y); o.s[6]=f2b(b.z); o.s[7]=f2b(b.w);
    *(uint4*)(out + i * 8) = o.u;
}

// ---------------------------------------------------------------------------
// W[K][N] fp32 -> Bt[n][k] bf16 for n < Npad (zero-fill n >= N). block 32x8.
// ---------------------------------------------------------------------------
__global__ __launch_bounds__(256) void transpose_cast(const float* __restrict__ W,
                                                      bf16_t* __restrict__ Bt,
                                                      int K, int N) {
    __shared__ float t[32][33];
    const int bx = blockIdx.x;   // n tile
    const int by = blockIdx.y;   // k tile
    const int tx = threadIdx.x, ty = threadIdx.y;
    const int n = bx * 32 + tx;
#pragma unroll
    for (int r = 0; r < 4; ++r) {
        int k = by * 32 + ty + r * 8;
        t[ty + r * 8][tx] = (n < N) ? W[(size_t)k * N + n] : 0.f;
    }
    __syncthreads();
#pragma unroll
    for (int r = 0; r < 4; ++r) {
        int nn = bx * 32 + ty + r * 8;
        Bt[(size_t)nn * K + by * 32 + tx] = f2b(t[tx][ty + r * 8]);
    }
}

// ---------------------------------------------------------------------------
// 256x256 8-phase MFMA GEMM (round-6 best config): C[M,N] = A[M,K] @ Bt[N,K]^T.
// 8 waves (2Mx4N), BK=64, 128 KiB LDS dbuf, XOR swizzle, counted vmcnt(4).
// ---------------------------------------------------------------------------
#define MM(a,b,c) __builtin_amdgcn_mfma_f32_16x16x32_bf16(a,b,c,0,0,0)

template<bool BF16OUT>
__global__ __launch_bounds__(512, 2) void gemm256(const bf16_t* __restrict__ A,
                                                  const bf16_t* __restrict__ Bt,
                                                  void* __restrict__ Cout,
                                                  int GX, int N, int K,
                                                  int lda, int ldb, int ldc) {
    __shared__ __align__(16) bf16_t Asm[2][256 * 64];   // 64 KiB
    __shared__ __align__(16) bf16_t Bsm[2][256 * 64];   // 64 KiB
    const int tid  = threadIdx.x;
    const int wid  = tid >> 6;
    const int lane = tid & 63;
    const int wm = wid >> 2;         // 0..1
    const int wn = wid & 3;          // 0..3

    // bijective XCD swizzle (m204)
    const int nwg = gridDim.x;
    const int wg  = blockIdx.x;
    const int q8 = nwg >> 3, r8 = nwg & 7;
    const int xcd = wg & 7, lo = wg >> 3;
    const int swz = (xcd < r8 ? xcd * (q8 + 1) : r8 * (q8 + 1) + (xcd - r8) * q8) + lo;
    const int bm = (swz / GX) * 256;
    const int bn = (swz % GX) * 256;

    // read-side frag addressing (XOR-swizzled chunk)
    const int fr  = lane & 15;
    const int kx0 = ((((lane >> 4))     ^ (lane & 7)) * 8);
    const int kx1 = ((((lane >> 4) + 4) ^ (lane & 7)) * 8);
    // stage-side per-lane source offset (inverse swizzle on global col)
    const int laneA  = lane >> 3;                         // row within 8-row stripe
    const int chunkS = ((lane & 7) ^ (lane >> 3)) * 8;    // pre-swizzled col chunk

    f32x4 acc[8][4];
#pragma unroll
    for (int i = 0; i < 8; ++i)
#pragma unroll
        for (int j = 0; j < 4; ++j) acc[i][j] = (f32x4){0.f, 0.f, 0.f, 0.f};

    short8 b00, b01, b10, b11, b20, b21, b30, b31;

#define STAGE_A(d, t, h) do { \
    const int r0_ = (h) * 128 + wid * 16; \
    gload_lds16(A + (size_t)(bm + r0_ +     laneA) * lda + (t) * 64 + chunkS, &Asm[d][(r0_    ) * 64]); \
    gload_lds16(A + (size_t)(bm + r0_ + 8 + laneA) * lda + (t) * 64 + chunkS, &Asm[d][(r0_ + 8) * 64]); \
} while (0)
#define STAGE_B(d, t, h) do { \
    const int r0_ = (h) * 128 + wid * 16; \
    gload_lds16(Bt + (size_t)(bn + r0_ +     laneA) * ldb + (t) * 64 + chunkS, &Bsm[d][(r0_    ) * 64]); \
    gload_lds16(Bt + (size_t)(bn + r0_ + 8 + laneA) * ldb + (t) * 64 + chunkS, &Bsm[d][(r0_ + 8) * 64]); \
} while (0)

// one phase: frag ds_reads | stage issue | barrier | 16 MFMA (compiler lgkm) | [vmcnt] | barrier
#define PHASE(curb, qq, DOVM, ...) do { \
    const bf16_t* Ab_ = &Asm[curb][(wm * 128 + (qq) * 32 + fr) * 64]; \
    short8 a00 = *(const short8*)(Ab_ + kx0); \
    short8 a01 = *(const short8*)(Ab_ + kx1); \
    short8 a10 = *(const short8*)(Ab_ + 16 * 64 + kx0); \
    short8 a11 = *(const short8*)(Ab_ + 16 * 64 + kx1); \
    if ((qq) == 0) { \
        const bf16_t* Bb_ = &Bsm[curb][(wn * 64 + fr) * 64]; \
        b00 = *(const short8*)(Bb_ + kx0);           b01 = *(const short8*)(Bb_ + kx1); \
        b10 = *(const short8*)(Bb_ + 16 * 64 + kx0); b11 = *(const short8*)(Bb_ + 16 * 64 + kx1); \
        b20 = *(const short8*)(Bb_ + 32 * 64 + kx0); b21 = *(const short8*)(Bb_ + 32 * 64 + kx1); \
        b30 = *(const short8*)(Bb_ + 48 * 64 + kx0); b31 = *(const short8*)(Bb_ + 48 * 64 + kx1); \
    } \
    __VA_ARGS__ \
    __builtin_amdgcn_sched_barrier(0); \
    __builtin_amdgcn_s_barrier(); \
    __builtin_amdgcn_s_setprio(1); \
    acc[(qq)*2  ][0] = MM(a00, b00, acc[(qq)*2  ][0]); acc[(qq)*2  ][0] = MM(a01, b01, acc[(qq)*2  ][0]); \
    acc[(qq)*2  ][1] = MM(a00, b10, acc[(qq)*2  ][1]); acc[(qq)*2  ][1] = MM(a01, b11, acc[(qq)*2  ][1]); \
    acc[(qq)*2  ][2] = MM(a00, b20, acc[(qq)*2  ][2]); acc[(qq)*2  ][2] = MM(a01, b21, acc[(qq)*2  ][2]); \
    acc[(qq)*2  ][3] = MM(a00, b30, acc[(qq)*2  ][3]); acc[(qq)*2  ][3] = MM(a01, b31, acc[(qq)*2  ][3]); \
    acc[(qq)*2+1][0] = MM(a10, b00, acc[(qq)*2+1][0]); acc[(qq)*2+1][0] = MM(a11, b01, acc[(qq)*2+1][0]); \
    acc[(qq)*2+1][1] = MM(a10, b10, acc[(qq)*2+1][1]); acc[(qq)*2+1][1] = MM(a11, b11, acc[(qq)*2+1][1]); \
    acc[(qq)*2+1][2] = MM(a10, b20, acc[(qq)*2+1][2]); acc[(qq)*2+1][2] = MM(a11, b21, acc[(qq)*2+1][2]); \
    acc[(qq)*2+1][3] = MM(a10, b30, acc[(qq)*2+1][3]); acc[(qq)*2+1][3] = MM(a11, b31, acc[(qq)*2+1][3]); \
    __builtin_amdgcn_s_setprio(0); \
    __builtin_amdgcn_sched_barrier(0); \
    if ((DOVM) == 1)      asm volatile("s_waitcnt vmcnt(4)" ::: "memory"); \
    else if ((DOVM) == 2) asm volatile("s_waitcnt vmcnt(0)" ::: "memory"); \
    __builtin_amdgcn_s_barrier(); \
} while (0)

    const int NT = K >> 6;        // K-tiles (BK=64); even
    const int NI = NT >> 1;       // 2 tiles per iteration

    // prologue: A(0), B(0), B(1); wait for A0,B0 (allow B1's 4 loads in flight)
    STAGE_A(0, 0, 0); STAGE_A(0, 0, 1);
    STAGE_B(0, 0, 0); STAGE_B(0, 0, 1);
    STAGE_B(1, 1, 0); STAGE_B(1, 1, 1);
    asm volatile("s_waitcnt vmcnt(4)" ::: "memory");
    __builtin_amdgcn_s_barrier();

    for (int i = 0; i < NI - 1; ++i) {
        const int t0 = 2 * i;
        PHASE(0, 0, 0, STAGE_A(1, t0 + 1, 0); );
        PHASE(0, 1, 0, STAGE_A(1, t0 + 1, 1); );
        PHASE(0, 2, 0, STAGE_B(0, t0 + 2, 0); );
        PHASE(0, 3, 1, STAGE_B(0, t0 + 2, 1); );
        PHASE(1, 0, 0, STAGE_A(0, t0 + 2, 0); );
        PHASE(1, 1, 0, STAGE_A(0, t0 + 2, 1); );
        PHASE(1, 2, 0, STAGE_B(1, t0 + 3, 0); );
        PHASE(1, 3, 1, STAGE_B(1, t0 + 3, 1); );
    }
    // epilogue: tiles NT-2 (buf0), NT-1 (buf1); stage only A(NT-1)
    PHASE(0, 0, 0, STAGE_A(1, NT - 1, 0); );
    PHASE(0, 1, 0, STAGE_A(1, NT - 1, 1); );
    PHASE(0, 2, 0, );
    PHASE(0, 3, 2, );
    PHASE(1, 0, 0, );
    PHASE(1, 1, 0, );
    PHASE(1, 2, 0, );
    PHASE(1, 3, 0, );

#undef PHASE
#undef STAGE_A
#undef STAGE_B

    const int crow4 = (lane >> 4) * 4, ccol = lane & 15;
#pragma unroll
    for (int mr = 0; mr < 8; ++mr)
#pragma unroll
        for (int nf = 0; nf < 4; ++nf) {
            const int gr = bm + wm * 128 + mr * 16 + crow4;
            const int gc = bn + wn * 64 + nf * 16 + ccol;
            if (gc < N) {
                if (BF16OUT) {
                    bf16_t* C = (bf16_t*)Cout;
#pragma unroll
                    for (int r = 0; r < 4; ++r)
                        C[(size_t)(gr + r) * ldc + gc] = f2b(acc[mr][nf][r]);
                } else {
                    float* C = (float*)Cout;
#pragma unroll
                    for (int r = 0; r < 4; ++r)
                        C[(size_t)(gr + r) * ldc + gc] = acc[mr][nf][r];
                }
            }
        }
}

// ---------------------------------------------------------------------------
// Depthwise causal conv (K=4) + SiLU, 8 channels x 4 rows per thread.
// ---------------------------------------------------------------------------
__global__ __launch_bounds__(256) void conv_silu(const bf16_t* __restrict__ zx,
                                                 const float* __restrict__ w,
                                                 const float* __restrict__ bias,
                                                 bf16_t* __restrict__ xconv) {
    const int c0 = (blockIdx.x * 256 + threadIdx.x) * 8;
    if (c0 >= CONVD) return;
    const int row0 = blockIdx.y * 4;
    float4 wv[8];
#pragma unroll
    for (int j = 0; j < 8; ++j) wv[j] = *(const float4*)(w + (size_t)(c0 + j) * 4);
    float bs[8];
    {
        float4 q0 = *(const float4*)(bias + c0), q1 = *(const float4*)(bias + c0 + 4);
        bs[0]=q0.x; bs[1]=q0.y; bs[2]=q0.z; bs[3]=q0.w;
        bs[4]=q1.x; bs[5]=q1.y; bs[6]=q1.z; bs[7]=q1.w;
    }
    U4 zin[7];
#pragma unroll
    for (int d = 0; d < 7; ++d) {
        int rr = row0 - 3 + d;
        if (rr >= 0) zin[d].u = *(const uint4*)(zx + (size_t)rr * DPROJ + DINNER + c0);
        else         zin[d].u = make_uint4(0, 0, 0, 0);
    }
    const int l0 = row0 & (LSEQ - 1);   // l0+r never wraps (row0 % 4 == 0)
#pragma unroll
    for (int r = 0; r < 4; ++r) {
        U4 o;
#pragma unroll
        for (int j = 0; j < 8; ++j) {
            float a = bs[j];
            const float* wj = (const float*)&wv[j];
#pragma unroll
            for (int k = 0; k < 4; ++k)
                if (l0 + r + k - 3 >= 0)
                    a += wj[k] * b2f(zin[r + k].s[j]);
            o.s[j] = f2b(a / (1.f + __expf(-a)));
        }
        *(uint4*)(xconv + (size_t)(row0 + r) * CONVD + c0) = o.u;
    }
}

__global__ void dt_softplus(const bf16_t* __restrict__ zx, const float* __restrict__ dt_bias,
                            float* __restrict__ dts) {
    const int idx = blockIdx.x * 256 + threadIdx.x;   // MROWS*NHEADS total
    const int h = idx & 63;
    const int row = idx >> 6;
    float x = b2f(zx[(size_t)row * DPROJ + DINNER + CONVD + h]) + dt_bias[h];
    dts[idx] = (x > 20.f) ? x : log1pf(__expf(x));
}

// ---------------------------------------------------------------------------
// Per (b,chunk,head): cumsum(dt*A) -> A_cs; chunk states via MFMA.
// ---------------------------------------------------------------------------
__global__ __launch_bounds__(256) void chunk_state(const bf16_t* __restrict__ xconv,
                                                   const float* __restrict__ dts,
                                                   const float* __restrict__ A_log,
                                                   float* __restrict__ A_cs_g,
                                                   float* __restrict__ states) {
    const int h = blockIdx.x, cc = blockIdx.y, b = blockIdx.z;
    const int tid = threadIdx.x, wid = tid >> 6, lane = tid & 63;
    __shared__ float cs[CHUNK];
    __shared__ __align__(16) bf16_t xwT[HDIM][CHUNK + 8];    // 33.8 KB
    __shared__ __align__(16) bf16_t BvT[DSTATE][CHUNK + 8];  // 67.6 KB
    const int rowbase = b * LSEQ + cc * CHUNK;

    const float dtv = dts[(size_t)(rowbase + tid) * NHEADS + h];
    const float Ah = -__expf(A_log[h]);
    cs[tid] = dtv * Ah;
    __syncthreads();
    for (int off = 1; off < CHUNK; off <<= 1) {
        float v = (tid >= off) ? cs[tid - off] : 0.f;
        __syncthreads();
        cs[tid] += v;
        __syncthreads();
    }
    const size_t acs_base = ((size_t)((b * NCHUNK + cc) * NHEADS + h)) * CHUNK;
    A_cs_g[acs_base + tid] = cs[tid];
    const float w_ = __expf(cs[CHUNK - 1] - cs[tid]) * dtv;  // decay*dt, <= dt

    {
        const bf16_t* xr = xconv + (size_t)(rowbase + tid) * CONVD + h * HDIM;
#pragma unroll
        for (int p8 = 0; p8 < 8; ++p8) {
            U4 v; v.u = *(const uint4*)(xr + p8 * 8);
#pragma unroll
            for (int j = 0; j < 8; ++j) xwT[p8 * 8 + j][tid] = f2b(b2f(v.s[j]) * w_);
        }
        const bf16_t* br = xconv + (size_t)(rowbase + tid) * CONVD + DINNER;
#pragma unroll
        for (int n8 = 0; n8 < 16; ++n8) {
            U4 v; v.u = *(const uint4*)(br + n8 * 8);
#pragma unroll
            for (int j = 0; j < 8; ++j) BvT[n8 * 8 + j][tid] = v.s[j];
        }
    }
    __syncthreads();

    const int fr = lane & 15, fk8 = (lane >> 4) * 8;
    f32x4 acc[4][2];
#pragma unroll
    for (int i = 0; i < 4; ++i)
#pragma unroll
        for (int j = 0; j < 2; ++j) acc[i][j] = (f32x4){0.f, 0.f, 0.f, 0.f};

#pragma unroll
    for (int ks = 0; ks < 8; ++ks) {
        const int k0 = ks * 32 + fk8;
        short8 av[4], bv[2];
#pragma unroll
        for (int mi = 0; mi < 4; ++mi)
            av[mi] = *(const short8*)&xwT[mi * 16 + fr][k0];
#pragma unroll
        for (int ni = 0; ni < 2; ++ni)
            bv[ni] = *(const short8*)&BvT[wid * 32 + ni * 16 + fr][k0];
#pragma unroll
        for (int mi = 0; mi < 4; ++mi)
#pragma unroll
            for (int ni = 0; ni < 2; ++ni)
                acc[mi][ni] = __builtin_amdgcn_mfma_f32_16x16x32_bf16(
                    av[mi], bv[ni], acc[mi][ni], 0, 0, 0);
    }
    float* st = states + ((size_t)((b * NCHUNK + cc) * NHEADS + h)) * (HDIM * DSTATE);
    const int crow4 = (lane >> 4) * 4, ccol = lane & 15;
#pragma unroll
    for (int mi = 0; mi < 4; ++mi)
#pragma unroll
        for (int ni = 0; ni < 2; ++ni)
#pragma unroll
            for (int r = 0; r < 4; ++r)
                st[(size_t)(mi * 16 + crow4 + r) * DSTATE + wid * 32 + ni * 16 + ccol] =
                    acc[mi][ni][r];
}

// ---------------------------------------------------------------------------
// Sequential inter-chunk scan; rewrites states[c] with prev_state (in place).
// ---------------------------------------------------------------------------
__global__ __launch_bounds__(256) void state_scan(float* __restrict__ states,
                                                  const float* __restrict__ A_cs_g) {
    const int h = blockIdx.x, piece = blockIdx.y, b = blockIdx.z;
    const int tid = threadIdx.x;
    float S[4] = {0.f, 0.f, 0.f, 0.f};
    for (int c = 0; c < NCHUNK; ++c) {
        const size_t sbase = ((size_t)((b * NCHUNK + c) * NHEADS + h)) * (HDIM * DSTATE)
                           + (size_t)piece * 1024;
        const float decay = __expf(A_cs_g[((size_t)((b * NCHUNK + c) * NHEADS + h)) * CHUNK + CHUNK - 1]);
#pragma unroll
        for (int i = 0; i < 4; ++i) {
            size_t idx = sbase + i * 256 + tid;
            float v = states[idx];
            states[idx] = S[i];
            S[i] = S[i] * decay + v;
        }
    }
}

// ---------------------------------------------------------------------------
// CB tile (lt,st): one 64x64 tile per block, pure-register MFMA (K=128).
// ---------------------------------------------------------------------------
__global__ __launch_bounds__(256) void cb_mfma(const bf16_t* __restrict__ xconv,
                                               float* __restrict__ CBg) {
    const int pi = blockIdx.x, cc = blockIdx.y, b = blockIdx.z;
    const int lt = (pi >= 6) ? 3 : (pi >= 3) ? 2 : (pi >= 1) ? 1 : 0;
    const int st = pi - ((lt * (lt + 1)) >> 1);
    const int tid = threadIdx.x, wid = tid >> 6, lane = tid & 63;
    const int rowbase = b * LSEQ + cc * CHUNK;
    const int fr = lane & 15, fk8 = (lane >> 4) * 8;

    const bf16_t* Crow = xconv + (size_t)(rowbase + lt * 64 + wid * 16) * CONVD + DINNER + DSTATE;
    const bf16_t* Brow = xconv + (size_t)(rowbase + st * 64) * CONVD + DINNER;

    f32x4 acc[4];
#pragma unroll
    for (int i = 0; i < 4; ++i) acc[i] = (f32x4){0.f, 0.f, 0.f, 0.f};

#pragma unroll
    for (int kk = 0; kk < 4; ++kk) {
        const int k0 = kk * 32 + fk8;
        short8 av = *(const short8*)(Crow + (size_t)fr * CONVD + k0);
        short8 bv[4];
#pragma unroll
        for (int ni = 0; ni < 4; ++ni)
            bv[ni] = *(const short8*)(Brow + (size_t)(ni * 16 + fr) * CONVD + k0);
#pragma unroll
        for (int ni = 0; ni < 4; ++ni)
            acc[ni] = __builtin_amdgcn_mfma_f32_16x16x32_bf16(av, bv[ni], acc[ni], 0, 0, 0);
    }
    float* out = CBg + ((size_t)(b * NCHUNK + cc)) * CHUNK * CHUNK;
    const int crow4 = (lane >> 4) * 4, ccol = lane & 15;
#pragma unroll
    for (int ni = 0; ni < 4; ++ni)
#pragma unroll
        for (int r = 0; r < 4; ++r)
            out[(size_t)(lt * 64 + wid * 16 + crow4 + r) * CHUNK + st * 64 + ni * 16 + ccol] =
                acc[ni][r];
}

// ---------------------------------------------------------------------------
// y via MFMA, wave-balanced: wave w owns 16-row groups {mi*64 + 16w}.
// Causal triangle splits evenly: every wave fills/multiplies the same volume.
// ---------------------------------------------------------------------------
__global__ __launch_bounds__(256) void y_mfma(const bf16_t* __restrict__ xconv,
                                              const float* __restrict__ dts,
                                              const float* __restrict__ A_cs_g,
                                              const float* __restrict__ prev_states,
                                              const float* __restrict__ CBg,
                                              const float* __restrict__ Dv,
                                              bf16_t* __restrict__ zx) {
    const int h = blockIdx.x, cc = blockIdx.y, b = blockIdx.z;
    const int tid = threadIdx.x, wid = tid >> 6, lane = tid & 63;
    __shared__ float Acs_s[CHUNK];
    __shared__ __align__(16) bf16_t xdtT[HDIM][CHUNK + 8];   // [p][s], 33 KB
    __shared__ __align__(16) bf16_t Pt[4][16][72];           // per-wave 16-row P strip, 9 KB
    const int rowbase = b * LSEQ + cc * CHUNK;
    const size_t acs_base = ((size_t)((b * NCHUNK + cc) * NHEADS + h)) * CHUNK;

    Acs_s[tid] = A_cs_g[acs_base + tid];
    {
        float dtv = dts[(size_t)(rowbase + tid) * NHEADS + h];
        const bf16_t* xr = xconv + (size_t)(rowbase + tid) * CONVD + h * HDIM;
#pragma unroll
        for (int p8 = 0; p8 < 8; ++p8) {
            U4 v; v.u = *(const uint4*)(xr + p8 * 8);
#pragma unroll
            for (int j = 0; j < 8; ++j)
                xdtT[p8 * 8 + j][tid] = f2b(b2f(v.s[j]) * dtv);
        }
    }
    __syncthreads();

    const int fr = lane & 15, fk8 = (lane >> 4) * 8;
    f32x4 acc[4][4];
#pragma unroll
    for (int i = 0; i < 4; ++i)
#pragma unroll
        for (int j = 0; j < 4; ++j) acc[i][j] = (f32x4){0.f, 0.f, 0.f, 0.f};

    // ---- Y_off = C @ prev^T via MFMA (K = 128); frag mi = rows mi*64+wid*16 ----
    const bf16_t* Cbase = xconv + (size_t)rowbase * CONVD + DINNER + DSTATE;
    const float* prev = prev_states + ((size_t)((b * NCHUNK + cc) * NHEADS + h)) * (HDIM * DSTATE);
#pragma unroll
    for (int kk = 0; kk < 4; ++kk) {
        const int k0 = kk * 32 + fk8;
        short8 av[4], bv[4];
#pragma unroll
        for (int mi = 0; mi < 4; ++mi)
            av[mi] = *(const short8*)(Cbase + (size_t)(mi * 64 + wid * 16 + fr) * CONVD + k0);
#pragma unroll
        for (int ni = 0; ni < 4; ++ni) {
            const float* pr = prev + (size_t)(ni * 16 + fr) * DSTATE + k0;
            float4 f0 = *(const float4*)pr;
            float4 f1 = *(const float4*)(pr + 4);
            S8 t;
            t.s[0]=f2b(f0.x); t.s[1]=f2b(f0.y); t.s[2]=f2b(f0.z); t.s[3]=f2b(f0.w);
            t.s[4]=f2b(f1.x); t.s[5]=f2b(f1.y); t.s[6]=f2b(f1.z); t.s[7]=f2b(f1.w);
            bv[ni] = t.v;
        }
#pragma unroll
        for (int mi = 0; mi < 4; ++mi)
#pragma unroll
            for (int ni = 0; ni < 4; ++ni)
                acc[mi][ni] = __builtin_amdgcn_mfma_f32_16x16x32_bf16(
                    av[mi], bv[ni], acc[mi][ni], 0, 0, 0);
    }

    // scale Y_off rows by exp(Acs[l]) (<= 1)
    const int crow4 = (lane >> 4) * 4, ccol = lane & 15;
#pragma unroll
    for (int mi = 0; mi < 4; ++mi) {
        float e[4];
#pragma unroll
        for (int r = 0; r < 4; ++r)
            e[r] = __expf(Acs_s[mi * 64 + wid * 16 + crow4 + r]);
#pragma unroll
        for (int ni = 0; ni < 4; ++ni)
#pragma unroll
            for (int r = 0; r < 4; ++r) acc[mi][ni][r] *= e[r];
    }

    // ---- Y_diag: per m-frag mi, s-tiles 0..mi; 16-row P strip per wave ----
    const float* cbb = CBg + ((size_t)(b * NCHUNK + cc)) * CHUNK * CHUNK;
    bf16_t (*Pw)[72] = Pt[wid];
#pragma unroll
    for (int mi = 0; mi < 4; ++mi) {
        const int lbase = mi * 64 + wid * 16;
        for (int st = 0; st <= mi; ++st) {
            const int s0 = st * 64;
            const float as_l = Acs_s[s0 + lane];
            __asm__ volatile("s_waitcnt lgkmcnt(0)" ::: "memory");  // WAR vs prior frag reads
            __builtin_amdgcn_sched_barrier(0);
#pragma unroll
            for (int e = 0; e < 16; ++e) {
                const int gl = lbase + e;
                float cbv = cbb[(size_t)gl * CHUNK + s0 + lane];
                float pv = cbv * __expf(Acs_s[gl] - as_l);
                if (st == mi && (s0 + lane) > gl) pv = 0.f;   // causal mask (kills poison too)
                Pw[e][lane] = f2b(pv);
            }
            __asm__ volatile("s_waitcnt lgkmcnt(0)" ::: "memory");  // RAW: fill -> frag reads
            __builtin_amdgcn_sched_barrier(0);
#pragma unroll
            for (int ks = 0; ks < 2; ++ks) {
                short8 av = *(const short8*)&Pw[fr][ks * 32 + fk8];
                short8 bv[4];
#pragma unroll
                for (int ni = 0; ni < 4; ++ni)
                    bv[ni] = *(const short8*)&xdtT[ni * 16 + fr][s0 + ks * 32 + fk8];
#pragma unroll
                for (int ni = 0; ni < 4; ++ni)
                    acc[mi][ni] = __builtin_amdgcn_mfma_f32_16x16x32_bf16(
                        av, bv[ni], acc[mi][ni], 0, 0, 0);
            }
        }
    }

    // ---- epilogue: + x*D, gate silu(z), write bf16 ----
    const float Dh = Dv[h];
#pragma unroll
    for (int mi = 0; mi < 4; ++mi)
#pragma unroll
        for (int ni = 0; ni < 4; ++ni) {
            const int p = ni * 16 + ccol;
#pragma unroll
            for (int r = 0; r < 4; ++r) {
                const int l = mi * 64 + wid * 16 + crow4 + r;
                const size_t row = (size_t)rowbase + l;
                float xr = b2f(xconv[row * CONVD + h * HDIM + p]);
                float zv = b2f(zx[row * DPROJ + h * HDIM + p]);
                float y = (acc[mi][ni][r] + xr * Dh) * (zv / (1.f + __expf(-zv)));
                zx[row * DPROJ + DINNER + h * HDIM + p] = f2b(y);
            }
        }
}

// ---------------------------------------------------------------------------
// RMSNorm row-wise over the y columns (DINNER..), result into cols 0..DINNER.
// ---------------------------------------------------------------------------
__global__ __launch_bounds__(256) void rmsnorm(bf16_t* __restrict__ zx, const float* __restrict__ nw) {
    const int row = blockIdx.x;
    const int tid = threadIdx.x;
    float fv[16];
    float ss = 0.f;
#pragma unroll
    for (int it = 0; it < 2; ++it) {
        int j0 = (it * 256 + tid) * 8;
        U4 v; v.u = *(const uint4*)(zx + (size_t)row * DPROJ + DINNER + j0);
#pragma unroll
        for (int j = 0; j < 8; ++j) { float f = b2f(v.s[j]); fv[it * 8 + j] = f; ss += f * f; }
    }
#pragma unroll
    for (int off = 32; off > 0; off >>= 1) ss += __shfl_down(ss, off, 64);
    __shared__ float red[4];
    if ((tid & 63) == 0) red[tid >> 6] = ss;
    __syncthreads();
    float tot = red[0] + red[1] + red[2] + red[3];
    float inv = rsqrtf(tot / (float)DINNER + 1e-5f);
#pragma unroll
    for (int it = 0; it < 2; ++it) {
        int j0 = (it * 256 + tid) * 8;
        U4 o;
#pragma unroll
        for (int j = 0; j < 8; ++j) o.s[j] = f2b(fv[it * 8 + j] * inv * nw[j0 + j]);
        *(uint4*)(zx + (size_t)row * DPROJ + j0) = o.u;
    }
}

// ---------------------------------------------------------------------------
extern "C" void kernel_launch(void* const* d_in, const int* in_sizes, int n_in,
                              void* d_out, int out_size, void* d_ws, size_t ws_size,
                              hipStream_t stream) {
    const float* u       = (const float*)d_in[0];
    const float* Win     = (const float*)d_in[1];
    const float* convw   = (const float*)d_in[2];
    const float* convb   = (const float*)d_in[3];
    const float* dt_bias = (const float*)d_in[4];
    const float* A_log   = (const float*)d_in[5];
    const float* Dv      = (const float*)d_in[6];
    const float* nw      = (const float*)d_in[7];
    const float* Wout    = (const float*)d_in[8];
    float* out = (float*)d_out;

    // ws map: zx bf16 (133MiB) + xconv bf16 (68MiB) + fp32 small (12MiB) ~213MiB
    bf16_t* zx    = (bf16_t*)d_ws;
    bf16_t* xconv = zx + (size_t)MROWS * DPROJ;
    float*  dts   = (float*)(xconv + (size_t)MROWS * CONVD);
    float*  acs   = dts + (size_t)MROWS * NHEADS;
    float*  cb    = acs + (size_t)BATCH * NCHUNK * NHEADS * CHUNK;

    // time-disjoint overlays:
    bf16_t* Abf    = xconv;            // u cast (33.5MB), dead before conv_silu writes xconv
    bf16_t* Btin   = (bf16_t*)d_out;   // Win^T (35.7MB), dead before chunk_state writes states
    float*  states = (float*)d_out;    // 64MB, dead before out_proj writes d_out
    bf16_t* Btout  = xconv;            // Wout^T (16.8MB), written after y_mfma frees xconv

    // 0a. cast u -> bf16
    cast_bf16<<<(MROWS * DMODEL / 8 + 255) / 256, 256, 0, stream>>>(u, Abf, (size_t)MROWS * DMODEL / 8);
    // 0b. Win [2048][8512] -> Btin [8704][2048] (zero-padded rows)
    transpose_cast<<<dim3(NPAD2 / 32, DMODEL / 32), dim3(32, 8), 0, stream>>>(Win, Btin, DMODEL, DPROJ);
    // 1. in_proj (256x256 8-phase MFMA) -> zx bf16
    gemm256<true><<<dim3((NPAD2 / 256) * (MROWS / 256)), 512, 0, stream>>>(
        Abf, Btin, zx, NPAD2 / 256, DPROJ, DMODEL, DMODEL, DMODEL, DPROJ);
    // 2. conv + silu ; dt softplus
    conv_silu<<<dim3((CONVD / 8 + 255) / 256, MROWS / 4), 256, 0, stream>>>(zx, convw, convb, xconv);
    dt_softplus<<<dim3(MROWS * NHEADS / 256), 256, 0, stream>>>(zx, dt_bias, dts);
    // 3. per-chunk cumsum + states (MFMA)
    chunk_state<<<dim3(NHEADS, NCHUNK, BATCH), 256, 0, stream>>>(xconv, dts, A_log, acs, states);
    // 4. inter-chunk scan (states -> prev_states in place)
    state_scan<<<dim3(NHEADS, 8, BATCH), 256, 0, stream>>>(states, acs);
    // 5. CB (MFMA, one tile per block)
    cb_mfma<<<dim3(10, NCHUNK, BATCH), 256, 0, stream>>>(xconv, cb);
    // 6. Y (diag + off + skip) gated, into zx — wave-balanced MFMA version
    y_mfma<<<dim3(NHEADS, NCHUNK, BATCH), 256, 0, stream>>>(xconv, dts, acs, states, cb, Dv, zx);
    // 7b. Wout [4096][2048] -> Btout [2048][4096] (xconv now dead)
    transpose_cast<<<dim3(DMODEL / 32, DINNER / 32), dim3(32, 8), 0, stream>>>(Wout, Btout, DINNER, DMODEL);
    // 7. RMSNorm
    rmsnorm<<<MROWS, 256, 0, stream>>>(zx, nw);
    // 8. out_proj (256x256 8-phase MFMA) -> fp32 out
    gemm256<false><<<dim3((DMODEL / 256) * (MROWS / 256)), 512, 0, stream>>>(
        zx, Btout, out, DMODEL / 256, DMODEL, DINNER, DPROJ, DINNER, DMODEL);
}

// Round 11
// 775.121 us; speedup vs baseline: 1.0251x; 1.0251x over previous
//
#include <hip/hip_runtime.h>
#include <cstddef>
#include <cstdint>
#include <math.h>

#define BATCH   2
#define LSEQ    4096
#define DMODEL  2048
#define DSTATE  128
#define HDIM    64
#define CHUNK   256
#define DINNER  4096
#define NHEADS  64
#define CONVD   4352
#define DPROJ   8512
#define NCHUNK  16
#define MROWS   (BATCH*LSEQ)
#define NPAD2   8704   // 34*256, padded N for in_proj (256-tile)

typedef unsigned short bf16_t;
union U4 { uint4 u; unsigned short s[8]; };

typedef __attribute__((ext_vector_type(8))) short short8;
typedef __attribute__((ext_vector_type(4))) float f32x4;
union S8 { short8 v; unsigned short s[8]; };

__device__ __forceinline__ float b2f(unsigned short u) {
    union { unsigned int i; float f; } v; v.i = ((unsigned int)u) << 16; return v.f;
}
__device__ __forceinline__ unsigned short f2b(float f) {
    union { float f; unsigned int i; } v; v.f = f;
    unsigned int r = v.i + 0x7fffu + ((v.i >> 16) & 1u);   // round-to-nearest-even
    return (unsigned short)(r >> 16);
}

// async global->LDS, 16B per lane; LDS dest = wave-uniform base + lane*16 (HW)
__device__ __forceinline__ void gload_lds16(const void* g, void* l) {
    auto gp = reinterpret_cast<const __attribute__((address_space(1))) unsigned int*>(
        reinterpret_cast<uintptr_t>(g));
    auto lp = reinterpret_cast<__attribute__((address_space(3))) unsigned int*>(
        reinterpret_cast<uintptr_t>(l));
    __builtin_amdgcn_global_load_lds(gp, lp, 16, 0, 0);
}

// ---------------------------------------------------------------------------
// cast u (fp32) -> bf16, contiguous
// ---------------------------------------------------------------------------
__global__ __launch_bounds__(256) void cast_bf16(const float* __restrict__ in,
                                                 bf16_t* __restrict__ out, size_t n8) {
    size_t i = (size_t)blockIdx.x * 256 + threadIdx.x;
    if (i >= n8) return;
    const float4 a = *(const float4*)(in + i * 8);
    const float4 b = *(const float4*)(in + i * 8 + 4);
    U4 o;
    o.s[0]=f2b(a.x); o.s[1]=f2b(a.y); o.s[2]=f2b(a.z); o.s[3]=f2b(a.w);
    o.s[4]=f2b(b.x); o.s[5]=f2b(b.y); o.s[6]=f2b(b.z); o.s[7]=f2b(b.w);
    *(uint4*)(out + i * 8) = o.u;
}

// ---------------------------------------------------------------------------
// W[K][N] fp32 -> Bt[n][k] bf16 for n < Npad (zero-fill n >= N). block 32x8.
// ---------------------------------------------------------------------------
__global__ __launch_bounds__(256) void transpose_cast(const float* __restrict__ W,
                                                      bf16_t* __restrict__ Bt,
                                                      int K, int N) {
    __shared__ float t[32][33];
    const int bx = blockIdx.x;   // n tile
    const int by = blockIdx.y;   // k tile
    const int tx = threadIdx.x, ty = threadIdx.y;
    const int n = bx * 32 + tx;
#pragma unroll
    for (int r = 0; r < 4; ++r) {
        int k = by * 32 + ty + r * 8;
        t[ty + r * 8][tx] = (n < N) ? W[(size_t)k * N + n] : 0.f;
    }
    __syncthreads();
#pragma unroll
    for (int r = 0; r < 4; ++r) {
        int nn = bx * 32 + ty + r * 8;
        Bt[(size_t)nn * K + by * 32 + tx] = f2b(t[tx][ty + r * 8]);
    }
}

// ---------------------------------------------------------------------------
// 256x256 8-phase MFMA GEMM (m201-style): C[M,N] = A[M,K] @ Bt[N,K]^T.
// 8 waves (2Mx4N), BK=64, 128 KiB LDS dbuf, st-XOR swizzle, counted vmcnt.
// ---------------------------------------------------------------------------
#define MM(a,b,c) __builtin_amdgcn_mfma_f32_16x16x32_bf16(a,b,c,0,0,0)

template<bool BF16OUT>
__global__ __launch_bounds__(512, 2) void gemm256(const bf16_t* __restrict__ A,
                                                  const bf16_t* __restrict__ Bt,
                                                  void* __restrict__ Cout,
                                                  int GX, int N, int K,
                                                  int lda, int ldb, int ldc) {
    __shared__ __align__(16) bf16_t Asm[2][256 * 64];   // 64 KiB
    __shared__ __align__(16) bf16_t Bsm[2][256 * 64];   // 64 KiB
    const int tid  = threadIdx.x;
    const int wid  = tid >> 6;
    const int lane = tid & 63;
    const int wm = wid >> 2;         // 0..1
    const int wn = wid & 3;          // 0..3

    // bijective XCD swizzle (m204)
    const int nwg = gridDim.x;
    const int wg  = blockIdx.x;
    const int q8 = nwg >> 3, r8 = nwg & 7;
    const int xcd = wg & 7, lo = wg >> 3;
    const int swz = (xcd < r8 ? xcd * (q8 + 1) : r8 * (q8 + 1) + (xcd - r8) * q8) + lo;
    const int bm = (swz / GX) * 256;
    const int bn = (swz % GX) * 256;

    // read-side frag addressing (XOR-swizzled chunk)
    const int fr  = lane & 15;
    const int kx0 = ((((lane >> 4))     ^ (lane & 7)) * 8);
    const int kx1 = ((((lane >> 4) + 4) ^ (lane & 7)) * 8);
    // stage-side per-lane source offset (inverse swizzle on global col)
    const int laneA  = lane >> 3;                         // row within 8-row stripe
    const int chunkS = ((lane & 7) ^ (lane >> 3)) * 8;    // pre-swizzled col chunk

    f32x4 acc[8][4];
#pragma unroll
    for (int i = 0; i < 8; ++i)
#pragma unroll
        for (int j = 0; j < 4; ++j) acc[i][j] = (f32x4){0.f, 0.f, 0.f, 0.f};

    short8 b00, b01, b10, b11, b20, b21, b30, b31;

#define STAGE_A(d, t, h) do { \
    const int r0_ = (h) * 128 + wid * 16; \
    gload_lds16(A + (size_t)(bm + r0_ +     laneA) * lda + (t) * 64 + chunkS, &Asm[d][(r0_    ) * 64]); \
    gload_lds16(A + (size_t)(bm + r0_ + 8 + laneA) * lda + (t) * 64 + chunkS, &Asm[d][(r0_ + 8) * 64]); \
} while (0)
#define STAGE_B(d, t, h) do { \
    const int r0_ = (h) * 128 + wid * 16; \
    gload_lds16(Bt + (size_t)(bn + r0_ +     laneA) * ldb + (t) * 64 + chunkS, &Bsm[d][(r0_    ) * 64]); \
    gload_lds16(Bt + (size_t)(bn + r0_ + 8 + laneA) * ldb + (t) * 64 + chunkS, &Bsm[d][(r0_ + 8) * 64]); \
} while (0)

// one phase: frag ds_reads | stage issue | barrier | lgkm0 | 16 MFMA | [vmcnt] | barrier
#define PHASE(curb, qq, DOVM, ...) do { \
    const bf16_t* Ab_ = &Asm[curb][(wm * 128 + (qq) * 32 + fr) * 64]; \
    short8 a00 = *(const short8*)(Ab_ + kx0); \
    short8 a01 = *(const short8*)(Ab_ + kx1); \
    short8 a10 = *(const short8*)(Ab_ + 16 * 64 + kx0); \
    short8 a11 = *(const short8*)(Ab_ + 16 * 64 + kx1); \
    if ((qq) == 0) { \
        const bf16_t* Bb_ = &Bsm[curb][(wn * 64 + fr) * 64]; \
        b00 = *(const short8*)(Bb_ + kx0);           b01 = *(const short8*)(Bb_ + kx1); \
        b10 = *(const short8*)(Bb_ + 16 * 64 + kx0); b11 = *(const short8*)(Bb_ + 16 * 64 + kx1); \
        b20 = *(const short8*)(Bb_ + 32 * 64 + kx0); b21 = *(const short8*)(Bb_ + 32 * 64 + kx1); \
        b30 = *(const short8*)(Bb_ + 48 * 64 + kx0); b31 = *(const short8*)(Bb_ + 48 * 64 + kx1); \
    } \
    __VA_ARGS__ \
    __builtin_amdgcn_sched_barrier(0); \
    __builtin_amdgcn_s_barrier(); \
    asm volatile("s_waitcnt lgkmcnt(0)" ::: "memory"); \
    __builtin_amdgcn_sched_barrier(0); \
    __builtin_amdgcn_s_setprio(1); \
    acc[(qq)*2  ][0] = MM(a00, b00, acc[(qq)*2  ][0]); acc[(qq)*2  ][0] = MM(a01, b01, acc[(qq)*2  ][0]); \
    acc[(qq)*2  ][1] = MM(a00, b10, acc[(qq)*2  ][1]); acc[(qq)*2  ][1] = MM(a01, b11, acc[(qq)*2  ][1]); \
    acc[(qq)*2  ][2] = MM(a00, b20, acc[(qq)*2  ][2]); acc[(qq)*2  ][2] = MM(a01, b21, acc[(qq)*2  ][2]); \
    acc[(qq)*2  ][3] = MM(a00, b30, acc[(qq)*2  ][3]); acc[(qq)*2  ][3] = MM(a01, b31, acc[(qq)*2  ][3]); \
    acc[(qq)*2+1][0] = MM(a10, b00, acc[(qq)*2+1][0]); acc[(qq)*2+1][0] = MM(a11, b01, acc[(qq)*2+1][0]); \
    acc[(qq)*2+1][1] = MM(a10, b10, acc[(qq)*2+1][1]); acc[(qq)*2+1][1] = MM(a11, b11, acc[(qq)*2+1][1]); \
    acc[(qq)*2+1][2] = MM(a10, b20, acc[(qq)*2+1][2]); acc[(qq)*2+1][2] = MM(a11, b21, acc[(qq)*2+1][2]); \
    acc[(qq)*2+1][3] = MM(a10, b30, acc[(qq)*2+1][3]); acc[(qq)*2+1][3] = MM(a11, b31, acc[(qq)*2+1][3]); \
    __builtin_amdgcn_s_setprio(0); \
    __builtin_amdgcn_sched_barrier(0); \
    if ((DOVM) == 1)      asm volatile("s_waitcnt vmcnt(4)" ::: "memory"); \
    else if ((DOVM) == 2) asm volatile("s_waitcnt vmcnt(0)" ::: "memory"); \
    __builtin_amdgcn_s_barrier(); \
} while (0)

    const int NT = K >> 6;        // K-tiles (BK=64); even
    const int NI = NT >> 1;       // 2 tiles per iteration

    // prologue: A(0), B(0), B(1); wait for A0,B0 (allow B1's 4 loads in flight)
    STAGE_A(0, 0, 0); STAGE_A(0, 0, 1);
    STAGE_B(0, 0, 0); STAGE_B(0, 0, 1);
    STAGE_B(1, 1, 0); STAGE_B(1, 1, 1);
    asm volatile("s_waitcnt vmcnt(4)" ::: "memory");
    __builtin_amdgcn_s_barrier();

    for (int i = 0; i < NI - 1; ++i) {
        const int t0 = 2 * i;
        PHASE(0, 0, 0, STAGE_A(1, t0 + 1, 0); );
        PHASE(0, 1, 0, STAGE_A(1, t0 + 1, 1); );
        PHASE(0, 2, 0, STAGE_B(0, t0 + 2, 0); );
        PHASE(0, 3, 1, STAGE_B(0, t0 + 2, 1); );
        PHASE(1, 0, 0, STAGE_A(0, t0 + 2, 0); );
        PHASE(1, 1, 0, STAGE_A(0, t0 + 2, 1); );
        PHASE(1, 2, 0, STAGE_B(1, t0 + 3, 0); );
        PHASE(1, 3, 1, STAGE_B(1, t0 + 3, 1); );
    }
    // epilogue: tiles NT-2 (buf0), NT-1 (buf1); stage only A(NT-1)
    PHASE(0, 0, 0, STAGE_A(1, NT - 1, 0); );
    PHASE(0, 1, 0, STAGE_A(1, NT - 1, 1); );
    PHASE(0, 2, 0, );
    PHASE(0, 3, 2, );
    PHASE(1, 0, 0, );
    PHASE(1, 1, 0, );
    PHASE(1, 2, 0, );
    PHASE(1, 3, 0, );

#undef PHASE
#undef STAGE_A
#undef STAGE_B

    const int crow4 = (lane >> 4) * 4, ccol = lane & 15;
#pragma unroll
    for (int mr = 0; mr < 8; ++mr)
#pragma unroll
        for (int nf = 0; nf < 4; ++nf) {
            const int gr = bm + wm * 128 + mr * 16 + crow4;
            const int gc = bn + wn * 64 + nf * 16 + ccol;
            if (gc < N) {
                if (BF16OUT) {
                    bf16_t* C = (bf16_t*)Cout;
#pragma unroll
                    for (int r = 0; r < 4; ++r)
                        C[(size_t)(gr + r) * ldc + gc] = f2b(acc[mr][nf][r]);
                } else {
                    float* C = (float*)Cout;
#pragma unroll
                    for (int r = 0; r < 4; ++r)
                        C[(size_t)(gr + r) * ldc + gc] = acc[mr][nf][r];
                }
            }
        }
}

// ---------------------------------------------------------------------------
// Depthwise causal conv (K=4) + SiLU, 8 channels x 4 rows per thread.
// ---------------------------------------------------------------------------
__global__ __launch_bounds__(256) void conv_silu(const bf16_t* __restrict__ zx,
                                                 const float* __restrict__ w,
                                                 const float* __restrict__ bias,
                                                 bf16_t* __restrict__ xconv) {
    const int c0 = (blockIdx.x * 256 + threadIdx.x) * 8;
    if (c0 >= CONVD) return;
    const int row0 = blockIdx.y * 4;
    float4 wv[8];
#pragma unroll
    for (int j = 0; j < 8; ++j) wv[j] = *(const float4*)(w + (size_t)(c0 + j) * 4);
    float bs[8];
    {
        float4 q0 = *(const float4*)(bias + c0), q1 = *(const float4*)(bias + c0 + 4);
        bs[0]=q0.x; bs[1]=q0.y; bs[2]=q0.z; bs[3]=q0.w;
        bs[4]=q1.x; bs[5]=q1.y; bs[6]=q1.z; bs[7]=q1.w;
    }
    U4 zin[7];
#pragma unroll
    for (int d = 0; d < 7; ++d) {
        int rr = row0 - 3 + d;
        if (rr >= 0) zin[d].u = *(const uint4*)(zx + (size_t)rr * DPROJ + DINNER + c0);
        else         zin[d].u = make_uint4(0, 0, 0, 0);
    }
    const int l0 = row0 & (LSEQ - 1);   // l0+r never wraps (row0 % 4 == 0)
#pragma unroll
    for (int r = 0; r < 4; ++r) {
        U4 o;
#pragma unroll
        for (int j = 0; j < 8; ++j) {
            float a = bs[j];
            const float* wj = (const float*)&wv[j];
#pragma unroll
            for (int k = 0; k < 4; ++k)
                if (l0 + r + k - 3 >= 0)
                    a += wj[k] * b2f(zin[r + k].s[j]);
            o.s[j] = f2b(a / (1.f + __expf(-a)));
        }
        *(uint4*)(xconv + (size_t)(row0 + r) * CONVD + c0) = o.u;
    }
}

__global__ void dt_softplus(const bf16_t* __restrict__ zx, const float* __restrict__ dt_bias,
                            float* __restrict__ dts) {
    const int idx = blockIdx.x * 256 + threadIdx.x;   // MROWS*NHEADS total
    const int h = idx & 63;
    const int row = idx >> 6;
    float x = b2f(zx[(size_t)row * DPROJ + DINNER + CONVD + h]) + dt_bias[h];
    dts[idx] = (x > 20.f) ? x : log1pf(__expf(x));
}

// ---------------------------------------------------------------------------
// Per (b,chunk,head): cumsum(dt*A) -> A_cs; chunk states via MFMA.
// ---------------------------------------------------------------------------
__global__ __launch_bounds__(256) void chunk_state(const bf16_t* __restrict__ xconv,
                                                   const float* __restrict__ dts,
                                                   const float* __restrict__ A_log,
                                                   float* __restrict__ A_cs_g,
                                                   float* __restrict__ states) {
    const int h = blockIdx.x, cc = blockIdx.y, b = blockIdx.z;
    const int tid = threadIdx.x, wid = tid >> 6, lane = tid & 63;
    __shared__ float cs[CHUNK];
    __shared__ __align__(16) bf16_t xwT[HDIM][CHUNK + 8];    // 33.8 KB
    __shared__ __align__(16) bf16_t BvT[DSTATE][CHUNK + 8];  // 67.6 KB
    const int rowbase = b * LSEQ + cc * CHUNK;

    const float dtv = dts[(size_t)(rowbase + tid) * NHEADS + h];
    const float Ah = -__expf(A_log[h]);
    cs[tid] = dtv * Ah;
    __syncthreads();
    for (int off = 1; off < CHUNK; off <<= 1) {
        float v = (tid >= off) ? cs[tid - off] : 0.f;
        __syncthreads();
        cs[tid] += v;
        __syncthreads();
    }
    const size_t acs_base = ((size_t)((b * NCHUNK + cc) * NHEADS + h)) * CHUNK;
    A_cs_g[acs_base + tid] = cs[tid];
    const float w_ = __expf(cs[CHUNK - 1] - cs[tid]) * dtv;  // decay*dt, <= dt

    {
        const bf16_t* xr = xconv + (size_t)(rowbase + tid) * CONVD + h * HDIM;
#pragma unroll
        for (int p8 = 0; p8 < 8; ++p8) {
            U4 v; v.u = *(const uint4*)(xr + p8 * 8);
#pragma unroll
            for (int j = 0; j < 8; ++j) xwT[p8 * 8 + j][tid] = f2b(b2f(v.s[j]) * w_);
        }
        const bf16_t* br = xconv + (size_t)(rowbase + tid) * CONVD + DINNER;
#pragma unroll
        for (int n8 = 0; n8 < 16; ++n8) {
            U4 v; v.u = *(const uint4*)(br + n8 * 8);
#pragma unroll
            for (int j = 0; j < 8; ++j) BvT[n8 * 8 + j][tid] = v.s[j];
        }
    }
    __syncthreads();

    const int fr = lane & 15, fk8 = (lane >> 4) * 8;
    f32x4 acc[4][2];
#pragma unroll
    for (int i = 0; i < 4; ++i)
#pragma unroll
        for (int j = 0; j < 2; ++j) acc[i][j] = (f32x4){0.f, 0.f, 0.f, 0.f};

#pragma unroll
    for (int ks = 0; ks < 8; ++ks) {
        const int k0 = ks * 32 + fk8;
        short8 av[4], bv[2];
#pragma unroll
        for (int mi = 0; mi < 4; ++mi)
            av[mi] = *(const short8*)&xwT[mi * 16 + fr][k0];
#pragma unroll
        for (int ni = 0; ni < 2; ++ni)
            bv[ni] = *(const short8*)&BvT[wid * 32 + ni * 16 + fr][k0];
#pragma unroll
        for (int mi = 0; mi < 4; ++mi)
#pragma unroll
            for (int ni = 0; ni < 2; ++ni)
                acc[mi][ni] = __builtin_amdgcn_mfma_f32_16x16x32_bf16(
                    av[mi], bv[ni], acc[mi][ni], 0, 0, 0);
    }
    float* st = states + ((size_t)((b * NCHUNK + cc) * NHEADS + h)) * (HDIM * DSTATE);
    const int crow4 = (lane >> 4) * 4, ccol = lane & 15;
#pragma unroll
    for (int mi = 0; mi < 4; ++mi)
#pragma unroll
        for (int ni = 0; ni < 2; ++ni)
#pragma unroll
            for (int r = 0; r < 4; ++r)
                st[(size_t)(mi * 16 + crow4 + r) * DSTATE + wid * 32 + ni * 16 + ccol] =
                    acc[mi][ni][r];
}

// ---------------------------------------------------------------------------
// Sequential inter-chunk scan; rewrites states[c] with prev_state (in place).
// ---------------------------------------------------------------------------
__global__ __launch_bounds__(256) void state_scan(float* __restrict__ states,
                                                  const float* __restrict__ A_cs_g) {
    const int h = blockIdx.x, piece = blockIdx.y, b = blockIdx.z;
    const int tid = threadIdx.x;
    float S[4] = {0.f, 0.f, 0.f, 0.f};
    for (int c = 0; c < NCHUNK; ++c) {
        const size_t sbase = ((size_t)((b * NCHUNK + c) * NHEADS + h)) * (HDIM * DSTATE)
                           + (size_t)piece * 1024;
        const float decay = __expf(A_cs_g[((size_t)((b * NCHUNK + c) * NHEADS + h)) * CHUNK + CHUNK - 1]);
#pragma unroll
        for (int i = 0; i < 4; ++i) {
            size_t idx = sbase + i * 256 + tid;
            float v = states[idx];
            states[idx] = S[i];
            S[i] = S[i] * decay + v;
        }
    }
}

// ---------------------------------------------------------------------------
// CB tile (lt,st): one 64x64 tile per block, pure-register MFMA (K=128).
// ---------------------------------------------------------------------------
__global__ __launch_bounds__(256) void cb_mfma(const bf16_t* __restrict__ xconv,
                                               float* __restrict__ CBg) {
    const int pi = blockIdx.x, cc = blockIdx.y, b = blockIdx.z;
    const int lt = (pi >= 6) ? 3 : (pi >= 3) ? 2 : (pi >= 1) ? 1 : 0;
    const int st = pi - ((lt * (lt + 1)) >> 1);
    const int tid = threadIdx.x, wid = tid >> 6, lane = tid & 63;
    const int rowbase = b * LSEQ + cc * CHUNK;
    const int fr = lane & 15, fk8 = (lane >> 4) * 8;

    const bf16_t* Crow = xconv + (size_t)(rowbase + lt * 64 + wid * 16) * CONVD + DINNER + DSTATE;
    const bf16_t* Brow = xconv + (size_t)(rowbase + st * 64) * CONVD + DINNER;

    f32x4 acc[4];
#pragma unroll
    for (int i = 0; i < 4; ++i) acc[i] = (f32x4){0.f, 0.f, 0.f, 0.f};

#pragma unroll
    for (int kk = 0; kk < 4; ++kk) {
        const int k0 = kk * 32 + fk8;
        short8 av = *(const short8*)(Crow + (size_t)fr * CONVD + k0);
        short8 bv[4];
#pragma unroll
        for (int ni = 0; ni < 4; ++ni)
            bv[ni] = *(const short8*)(Brow + (size_t)(ni * 16 + fr) * CONVD + k0);
#pragma unroll
        for (int ni = 0; ni < 4; ++ni)
            acc[ni] = __builtin_amdgcn_mfma_f32_16x16x32_bf16(av, bv[ni], acc[ni], 0, 0, 0);
    }
    float* out = CBg + ((size_t)(b * NCHUNK + cc)) * CHUNK * CHUNK;
    const int crow4 = (lane >> 4) * 4, ccol = lane & 15;
#pragma unroll
    for (int ni = 0; ni < 4; ++ni)
#pragma unroll
        for (int r = 0; r < 4; ++r)
            out[(size_t)(lt * 64 + wid * 16 + crow4 + r) * CHUNK + st * 64 + ni * 16 + ccol] =
                acc[ni][r];
}

// ---------------------------------------------------------------------------
// y via MFMA: per (h,cc,b) block, 4 waves; wave w owns rows [64w,64w+64).
// ---------------------------------------------------------------------------
__global__ __launch_bounds__(256) void y_mfma(const bf16_t* __restrict__ xconv,
                                              const float* __restrict__ dts,
                                              const float* __restrict__ A_cs_g,
                                              const float* __restrict__ prev_states,
                                              const float* __restrict__ CBg,
                                              const float* __restrict__ Dv,
                                              bf16_t* __restrict__ zx) {
    const int h = blockIdx.x, cc = blockIdx.y, b = blockIdx.z;
    const int tid = threadIdx.x, wid = tid >> 6, lane = tid & 63;
    __shared__ float Acs_s[CHUNK];
    __shared__ __align__(16) bf16_t xdtT[HDIM][CHUNK + 8];   // [p][s], 33 KB
    __shared__ __align__(16) bf16_t Pt[4][64][72];           // per-wave P tile, 36 KB
    const int rowbase = b * LSEQ + cc * CHUNK;
    const size_t acs_base = ((size_t)((b * NCHUNK + cc) * NHEADS + h)) * CHUNK;

    Acs_s[tid] = A_cs_g[acs_base + tid];
    {
        float dtv = dts[(size_t)(rowbase + tid) * NHEADS + h];
        const bf16_t* xr = xconv + (size_t)(rowbase + tid) * CONVD + h * HDIM;
#pragma unroll
        for (int p8 = 0; p8 < 8; ++p8) {
            U4 v; v.u = *(const uint4*)(xr + p8 * 8);
#pragma unroll
            for (int j = 0; j < 8; ++j)
                xdtT[p8 * 8 + j][tid] = f2b(b2f(v.s[j]) * dtv);
        }
    }
    __syncthreads();

    const int fr = lane & 15, fk8 = (lane >> 4) * 8;
    f32x4 acc[4][4];
#pragma unroll
    for (int i = 0; i < 4; ++i)
#pragma unroll
        for (int j = 0; j < 4; ++j) acc[i][j] = (f32x4){0.f, 0.f, 0.f, 0.f};

    // ---- Y_off = C @ prev^T via MFMA (K = 128, 4 k-steps) ----
    const bf16_t* Crow = xconv + (size_t)(rowbase + wid * 64) * CONVD + DINNER + DSTATE;
    const float* prev = prev_states + ((size_t)((b * NCHUNK + cc) * NHEADS + h)) * (HDIM * DSTATE);
#pragma unroll
    for (int kk = 0; kk < 4; ++kk) {
        const int k0 = kk * 32 + fk8;
        short8 av[4], bv[4];
#pragma unroll
        for (int mi = 0; mi < 4; ++mi)
            av[mi] = *(const short8*)(Crow + (size_t)(mi * 16 + fr) * CONVD + k0);
#pragma unroll
        for (int ni = 0; ni < 4; ++ni) {
            const float* pr = prev + (size_t)(ni * 16 + fr) * DSTATE + k0;
            float4 f0 = *(const float4*)pr;
            float4 f1 = *(const float4*)(pr + 4);
            S8 t;
            t.s[0]=f2b(f0.x); t.s[1]=f2b(f0.y); t.s[2]=f2b(f0.z); t.s[3]=f2b(f0.w);
            t.s[4]=f2b(f1.x); t.s[5]=f2b(f1.y); t.s[6]=f2b(f1.z); t.s[7]=f2b(f1.w);
            bv[ni] = t.v;
        }
#pragma unroll
        for (int mi = 0; mi < 4; ++mi)
#pragma unroll
            for (int ni = 0; ni < 4; ++ni)
                acc[mi][ni] = __builtin_amdgcn_mfma_f32_16x16x32_bf16(
                    av[mi], bv[ni], acc[mi][ni], 0, 0, 0);
    }

    // scale Y_off rows by exp(Acs[l]) (<= 1)
    const int crow4 = (lane >> 4) * 4, ccol = lane & 15;
#pragma unroll
    for (int mi = 0; mi < 4; ++mi) {
        float e[4];
#pragma unroll
        for (int r = 0; r < 4; ++r)
            e[r] = __expf(Acs_s[wid * 64 + mi * 16 + crow4 + r]);
#pragma unroll
        for (int ni = 0; ni < 4; ++ni)
#pragma unroll
            for (int r = 0; r < 4; ++r) acc[mi][ni][r] *= e[r];
    }

    // ---- Y_diag: s-tiles 0..wid; per-wave P tile, then MFMA vs xdtT ----
    const float* cbb = CBg + ((size_t)(b * NCHUNK + cc)) * CHUNK * CHUNK;
    for (int st = 0; st <= wid; ++st) {
        const int s0 = st * 64;
        const float as_l = Acs_s[s0 + lane];
        __asm__ volatile("s_waitcnt lgkmcnt(0)" ::: "memory");  // WAR vs prior frag reads
        __builtin_amdgcn_sched_barrier(0);
        for (int e = 0; e < 64; ++e) {
            const int gl = wid * 64 + e;
            float cbv = cbb[(size_t)gl * CHUNK + s0 + lane];
            float pv = cbv * __expf(Acs_s[gl] - as_l);
            if (st == wid && (s0 + lane) > gl) pv = 0.f;   // mask (also kills poison reads)
            Pt[wid][e][lane] = f2b(pv);
        }
        __asm__ volatile("s_waitcnt lgkmcnt(0)" ::: "memory");  // RAW: fill -> frag reads
        __builtin_amdgcn_sched_barrier(0);
#pragma unroll
        for (int ks = 0; ks < 2; ++ks) {
            short8 av[4], bv[4];
#pragma unroll
            for (int mi = 0; mi < 4; ++mi)
                av[mi] = *(const short8*)&Pt[wid][mi * 16 + fr][ks * 32 + fk8];
#pragma unroll
            for (int ni = 0; ni < 4; ++ni)
                bv[ni] = *(const short8*)&xdtT[ni * 16 + fr][s0 + ks * 32 + fk8];
#pragma unroll
            for (int mi = 0; mi < 4; ++mi)
#pragma unroll
                for (int ni = 0; ni < 4; ++ni)
                    acc[mi][ni] = __builtin_amdgcn_mfma_f32_16x16x32_bf16(
                        av[mi], bv[ni], acc[mi][ni], 0, 0, 0);
        }
    }

    // ---- epilogue: + x*D, gate silu(z), write bf16 ----
    const float Dh = Dv[h];
#pragma unroll
    for (int mi = 0; mi < 4; ++mi)
#pragma unroll
        for (int ni = 0; ni < 4; ++ni) {
            const int p = ni * 16 + ccol;
#pragma unroll
            for (int r = 0; r < 4; ++r) {
                const int l = wid * 64 + mi * 16 + crow4 + r;
                const size_t row = (size_t)rowbase + l;
                float xr = b2f(xconv[row * CONVD + h * HDIM + p]);
                float zv = b2f(zx[row * DPROJ + h * HDIM + p]);
                float y = (acc[mi][ni][r] + xr * Dh) * (zv / (1.f + __expf(-zv)));
                zx[row * DPROJ + DINNER + h * HDIM + p] = f2b(y);
            }
        }
}

// ---------------------------------------------------------------------------
// RMSNorm row-wise over the y columns (DINNER..), result into cols 0..DINNER.
// ---------------------------------------------------------------------------
__global__ __launch_bounds__(256) void rmsnorm(bf16_t* __restrict__ zx, const float* __restrict__ nw) {
    const int row = blockIdx.x;
    const int tid = threadIdx.x;
    float fv[16];
    float ss = 0.f;
#pragma unroll
    for (int it = 0; it < 2; ++it) {
        int j0 = (it * 256 + tid) * 8;
        U4 v; v.u = *(const uint4*)(zx + (size_t)row * DPROJ + DINNER + j0);
#pragma unroll
        for (int j = 0; j < 8; ++j) { float f = b2f(v.s[j]); fv[it * 8 + j] = f; ss += f * f; }
    }
#pragma unroll
    for (int off = 32; off > 0; off >>= 1) ss += __shfl_down(ss, off, 64);
    __shared__ float red[4];
    if ((tid & 63) == 0) red[tid >> 6] = ss;
    __syncthreads();
    float tot = red[0] + red[1] + red[2] + red[3];
    float inv = rsqrtf(tot / (float)DINNER + 1e-5f);
#pragma unroll
    for (int it = 0; it < 2; ++it) {
        int j0 = (it * 256 + tid) * 8;
        U4 o;
#pragma unroll
        for (int j = 0; j < 8; ++j) o.s[j] = f2b(fv[it * 8 + j] * inv * nw[j0 + j]);
        *(uint4*)(zx + (size_t)row * DPROJ + j0) = o.u;
    }
}

// ---------------------------------------------------------------------------
extern "C" void kernel_launch(void* const* d_in, const int* in_sizes, int n_in,
                              void* d_out, int out_size, void* d_ws, size_t ws_size,
                              hipStream_t stream) {
    const float* u       = (const float*)d_in[0];
    const float* Win     = (const float*)d_in[1];
    const float* convw   = (const float*)d_in[2];
    const float* convb   = (const float*)d_in[3];
    const float* dt_bias = (const float*)d_in[4];
    const float* A_log   = (const float*)d_in[5];
    const float* Dv      = (const float*)d_in[6];
    const float* nw      = (const float*)d_in[7];
    const float* Wout    = (const float*)d_in[8];
    float* out = (float*)d_out;

    // ws map: zx bf16 (133MiB) + xconv bf16 (68MiB) + fp32 small (12MiB) ~213MiB
    bf16_t* zx    = (bf16_t*)d_ws;
    bf16_t* xconv = zx + (size_t)MROWS * DPROJ;
    float*  dts   = (float*)(xconv + (size_t)MROWS * CONVD);
    float*  acs   = dts + (size_t)MROWS * NHEADS;
    float*  cb    = acs + (size_t)BATCH * NCHUNK * NHEADS * CHUNK;

    // time-disjoint overlays:
    bf16_t* Abf    = xconv;            // u cast (33.5MB), dead before conv_silu writes xconv
    bf16_t* Btin   = (bf16_t*)d_out;   // Win^T (35.7MB), dead before chunk_state writes states
    float*  states = (float*)d_out;    // 64MB, dead before out_proj writes d_out
    bf16_t* Btout  = xconv;            // Wout^T (16.8MB), written after y_mfma frees xconv

    // 0a. cast u -> bf16
    cast_bf16<<<(MROWS * DMODEL / 8 + 255) / 256, 256, 0, stream>>>(u, Abf, (size_t)MROWS * DMODEL / 8);
    // 0b. Win [2048][8512] -> Btin [8704][2048] (zero-padded rows)
    transpose_cast<<<dim3(NPAD2 / 32, DMODEL / 32), dim3(32, 8), 0, stream>>>(Win, Btin, DMODEL, DPROJ);
    // 1. in_proj (256x256 8-phase MFMA) -> zx bf16
    gemm256<true><<<dim3((NPAD2 / 256) * (MROWS / 256)), 512, 0, stream>>>(
        Abf, Btin, zx, NPAD2 / 256, DPROJ, DMODEL, DMODEL, DMODEL, DPROJ);
    // 2. conv + silu ; dt softplus
    conv_silu<<<dim3((CONVD / 8 + 255) / 256, MROWS / 4), 256, 0, stream>>>(zx, convw, convb, xconv);
    dt_softplus<<<dim3(MROWS * NHEADS / 256), 256, 0, stream>>>(zx, dt_bias, dts);
    // 3. per-chunk cumsum + states (MFMA)
    chunk_state<<<dim3(NHEADS, NCHUNK, BATCH), 256, 0, stream>>>(xconv, dts, A_log, acs, states);
    // 4. inter-chunk scan (states -> prev_states in place)
    state_scan<<<dim3(NHEADS, 8, BATCH), 256, 0, stream>>>(states, acs);
    // 5. CB (MFMA, one tile per block)
    cb_mfma<<<dim3(10, NCHUNK, BATCH), 256, 0, stream>>>(xconv, cb);
    // 6. Y (diag + off + skip) gated, into zx — MFMA version
    y_mfma<<<dim3(NHEADS, NCHUNK, BATCH), 256, 0, stream>>>(xconv, dts, acs, states, cb, Dv, zx);
    // 7b. Wout [4096][2048] -> Btout [2048][4096] (xconv now dead)
    transpose_cast<<<dim3(DMODEL / 32, DINNER / 32), dim3(32, 8), 0, stream>>>(Wout, Btout, DINNER, DMODEL);
    // 7. RMSNorm
    rmsnorm<<<MROWS, 256, 0, stream>>>(zx, nw);
    // 8. out_proj (256x256 8-phase MFMA) -> fp32 out
    gemm256<false><<<dim3((DMODEL / 256) * (MROWS / 256)), 512, 0, stream>>>(
        zx, Btout, out, DMODEL / 256, DMODEL, DINNER, DPROJ, DINNER, DMODEL);
}